// Round 1
// baseline (343.357 us; speedup 1.0000x reference)
//
#include <hip/hip_runtime.h>
#include <hip/hip_bf16.h>

// AttnPredictor, restructured:
//   q[b]   = a[b]@Wq + bq
//   ae[b]  = a[b]@Wav + bav
//   scores[b,d] = (z[b,d]*(Wk[d]·q[b]) + bk·q[b]) / sqrt(192);  w = softmax_d
//   U[h,d,k]  = Wfv[d,:]·W1[h,0:128,k]
//   c0[h,k]   = bfv·W1[h,0:128,k] + b1[h,k]
//   G[b,h,k]  = ae[b]·W1[h,128:192,k] + c0[h,k]
//   P[b,h,k]  = sum_d w[b,d]*relu(z[b,d]*U[h,d,k] + G[b,h,k])
//   M[h]      = W2[h]@W1o[h]  (valid since sum_d w = 1 lets b2 pass through)
//   c1[h,k2]  = b2[h]@W1o[h] + b1o[h]
//   h2        = relu(P@M + c1);  effect[b,h] = h2·W2o[h] + b2o[h]
//
// Workspace (floats): w 16384 | ae 32768 | U 262144 | c0 8192 | c1 8192 |
//                     M_T 2097152 | G 4194304   => ~26.5 MB total.

#define B_  512
#define D_  32
#define A_  18
#define FED_ 128
#define AED_ 64
#define VD_ 192
#define HID_ 256
#define H_  32

// ---------------------------------------------------------------- K1: q, ae, softmax w, attn_weights out
__global__ __launch_bounds__(64) void k1_prep(
    const float* __restrict__ feat, const float* __restrict__ act,
    const float* __restrict__ Wq, const float* __restrict__ bq,
    const float* __restrict__ Wk, const float* __restrict__ bk,
    const float* __restrict__ Wav, const float* __restrict__ bav,
    float* __restrict__ ws_w, float* __restrict__ ws_ae,
    float* __restrict__ out_aw) {
  const int b = blockIdx.x;
  const int t = threadIdx.x;
  __shared__ float sQ[192];
  __shared__ float sW[32];

  float a_reg[18];
#pragma unroll
  for (int j = 0; j < 18; ++j) a_reg[j] = act[b * 18 + j];

  // q[c], c = t, t+64, t+128
#pragma unroll
  for (int i = 0; i < 3; ++i) {
    const int c = i * 64 + t;
    float acc = bq[c];
#pragma unroll
    for (int j = 0; j < 18; ++j) acc += a_reg[j] * Wq[j * 192 + c];
    sQ[c] = acc;
  }
  // ae[e], e = t
  {
    float acc = bav[t];
#pragma unroll
    for (int j = 0; j < 18; ++j) acc += a_reg[j] * Wav[j * 64 + t];
    ws_ae[b * 64 + t] = acc;
  }
  __syncthreads();

  // lanes 0..31: dotk[d] = Wk[d]·q ; lane 32: dotb = bk·q
  float dot = 0.f;
  const float* row = (t < 32) ? (Wk + t * 192) : bk;
  if (t < 33) {
    for (int c4 = 0; c4 < 48; ++c4) {
      float4 r4 = *(const float4*)(row + c4 * 4);
      float4 q4 = *(const float4*)(sQ + c4 * 4);
      dot += r4.x * q4.x + r4.y * q4.y + r4.z * q4.z + r4.w * q4.w;
    }
  }
  const float dotb = __shfl(dot, 32, 64);

  float sc = 0.f;
  if (t < 32) sc = (feat[b * 32 + t] * dot + dotb) * 0.07216878364870322f; // 1/sqrt(192)
  float mx = sc;
#pragma unroll
  for (int off = 16; off >= 1; off >>= 1) mx = fmaxf(mx, __shfl_xor(mx, off, 32));
  float e = (t < 32) ? __expf(sc - mx) : 0.f;
  float s = e;
#pragma unroll
  for (int off = 16; off >= 1; off >>= 1) s += __shfl_xor(s, off, 32);
  const float w = e / s;
  if (t < 32) { ws_w[b * 32 + t] = w; sW[t] = w; }
  __syncthreads();

  // attn_weights[b,h,d] = w[d]
#pragma unroll
  for (int i = 0; i < 16; ++i) {
    const int j = i * 64 + t;
    out_aw[b * 1024 + j] = sW[j & 31];
  }
}

// ---------------------------------------------------------------- K2: c0[h,k], c1[h,k]
__global__ __launch_bounds__(256) void k2_biases(
    const float* __restrict__ W1, const float* __restrict__ b1,
    const float* __restrict__ bfv,
    const float* __restrict__ W1o, const float* __restrict__ b1o,
    const float* __restrict__ b2,
    float* __restrict__ ws_c0, float* __restrict__ ws_c1) {
  const int h = blockIdx.x;
  const int t = threadIdx.x;
  float c0 = b1[h * 256 + t];
  for (int f = 0; f < 128; ++f) c0 += bfv[f] * W1[(h * 192 + f) * 256 + t];
  ws_c0[h * 256 + t] = c0;
  float c1 = b1o[h * 256 + t];
  for (int v = 0; v < 192; ++v) c1 += b2[h * 192 + v] * W1o[(h * 192 + v) * 256 + t];
  ws_c1[h * 256 + t] = c1;
}

// ---------------------------------------------------------------- K3: U[h,d,k]
__global__ __launch_bounds__(256) void k3_U(
    const float* __restrict__ Wfv, const float* __restrict__ W1,
    float* __restrict__ ws_U) {
  const int bx = blockIdx.x;
  const int h = bx >> 2, dt = bx & 3;   // 8 d's per block
  const int t = threadIdx.x;
  __shared__ float sF[1024];            // [8][128] Wfv tile
#pragma unroll
  for (int i = 0; i < 4; ++i) sF[i * 256 + t] = Wfv[dt * 1024 + i * 256 + t];
  __syncthreads();
  float acc[8];
#pragma unroll
  for (int dd = 0; dd < 8; ++dd) acc[dd] = 0.f;
  for (int fc = 0; fc < 32; ++fc) {
    float w1v[4];
#pragma unroll
    for (int u = 0; u < 4; ++u) w1v[u] = W1[(h * 192 + fc * 4 + u) * 256 + t];
#pragma unroll
    for (int dd = 0; dd < 8; ++dd) {
      float4 f4 = *(const float4*)(sF + dd * 128 + fc * 4);
      acc[dd] += f4.x * w1v[0] + f4.y * w1v[1] + f4.z * w1v[2] + f4.w * w1v[3];
    }
  }
#pragma unroll
  for (int dd = 0; dd < 8; ++dd)
    ws_U[(h * 32 + dt * 8 + dd) * 256 + t] = acc[dd];
}

// ---------------------------------------------------------------- K4: M_T[h][k2][k1] = (W2[h]@W1o[h])^T
__global__ __launch_bounds__(256) void k4_M(
    const float* __restrict__ W2, const float* __restrict__ W1o,
    float* __restrict__ ws_M) {
  const int bx = blockIdx.x;
  const int h = bx >> 3, kt = bx & 7;   // k1 tile of 32
  const int t = threadIdx.x;
  __shared__ float s[8320];             // phase A: [32][192] W2 tile; phase B: [32][260] transpose
#pragma unroll
  for (int i = 0; i < 24; ++i)
    s[i * 256 + t] = W2[h * 49152 + kt * 6144 + i * 256 + t];
  __syncthreads();
  float acc[32];
#pragma unroll
  for (int r = 0; r < 32; ++r) acc[r] = 0.f;
  for (int vc = 0; vc < 48; ++vc) {
    float w1o[4];
#pragma unroll
    for (int u = 0; u < 4; ++u) w1o[u] = W1o[(h * 192 + vc * 4 + u) * 256 + t];
#pragma unroll
    for (int r = 0; r < 32; ++r) {
      float4 w2 = *(const float4*)(s + r * 192 + vc * 4);
      acc[r] += w2.x * w1o[0] + w2.y * w1o[1] + w2.z * w1o[2] + w2.w * w1o[3];
    }
  }
  __syncthreads();
#pragma unroll
  for (int r = 0; r < 32; ++r) s[r * 260 + t] = acc[r];
  __syncthreads();
  const int k1l = t & 31, k2g = t >> 5;
#pragma unroll
  for (int it = 0; it < 32; ++it) {
    const int k2 = it * 8 + k2g;
    ws_M[(h * 256 + k2) * 256 + kt * 32 + k1l] = s[k1l * 260 + k2];
  }
}

// ---------------------------------------------------------------- K5: G[b,h,k]
__global__ __launch_bounds__(256) void k5_G(
    const float* __restrict__ W1, const float* __restrict__ ws_ae,
    const float* __restrict__ ws_c0, float* __restrict__ ws_G) {
  const int bx = blockIdx.x;
  const int h = bx >> 4, bt = bx & 15;
  const int b0 = bt * 32;
  const int t = threadIdx.x;
  __shared__ float sAe[2048];           // [32 b][64 j]
#pragma unroll
  for (int i = 0; i < 8; ++i) sAe[i * 256 + t] = ws_ae[b0 * 64 + i * 256 + t];
  float w1r[64];
#pragma unroll
  for (int j = 0; j < 64; ++j) w1r[j] = W1[(h * 192 + 128 + j) * 256 + t];
  const float c0 = ws_c0[h * 256 + t];
  __syncthreads();
  for (int bi = 0; bi < 32; ++bi) {
    float acc = c0;
#pragma unroll
    for (int jc = 0; jc < 16; ++jc) {
      float4 a4 = *(const float4*)(sAe + bi * 64 + jc * 4);
      acc += a4.x * w1r[jc * 4 + 0] + a4.y * w1r[jc * 4 + 1]
           + a4.z * w1r[jc * 4 + 2] + a4.w * w1r[jc * 4 + 3];
    }
    ws_G[((b0 + bi) * 32 + h) * 256 + t] = acc;
  }
}

// ---------------------------------------------------------------- K6: main — P, h2 = relu(P@M+c1), effect
__global__ __launch_bounds__(256) void k6_main(
    const float* __restrict__ feat, const float* __restrict__ ws_w,
    const float* __restrict__ ws_U, const float* __restrict__ ws_G,
    const float* __restrict__ ws_M, const float* __restrict__ ws_c1,
    const float* __restrict__ W2o, const float* __restrict__ b2o,
    float* __restrict__ out_eff) {
  const int bx = blockIdx.x;
  const int h = bx >> 4, bt = bx & 15;
  const int b0 = bt * 32;
  const int t = threadIdx.x;
  __shared__ float sP[32 * 264];        // [32 b][256 k], pad to 264

  // ---- phase 1: P[bi][k] for thread's (bi = t>>3, k in [kg*32, kg*32+32))
  {
    const int bi = t >> 3, kg = t & 7;
    const int b = b0 + bi;
    float g[32], acc[32];
    const float* Gp = ws_G + (b * 32 + h) * 256 + kg * 32;
#pragma unroll
    for (int i = 0; i < 8; ++i) {
      float4 g4 = *(const float4*)(Gp + i * 4);
      g[i * 4 + 0] = g4.x; g[i * 4 + 1] = g4.y; g[i * 4 + 2] = g4.z; g[i * 4 + 3] = g4.w;
      acc[i * 4 + 0] = 0.f; acc[i * 4 + 1] = 0.f; acc[i * 4 + 2] = 0.f; acc[i * 4 + 3] = 0.f;
    }
    const float* Up = ws_U + h * 8192 + kg * 32;
    for (int dc = 0; dc < 8; ++dc) {
      float4 z4 = *(const float4*)(feat + b * 32 + dc * 4);
      float4 w4 = *(const float4*)(ws_w + b * 32 + dc * 4);
      float zz[4] = {z4.x, z4.y, z4.z, z4.w};
      float wv[4] = {w4.x, w4.y, w4.z, w4.w};
#pragma unroll
      for (int dd = 0; dd < 4; ++dd) {
        const float* Ud = Up + (dc * 4 + dd) * 256;
#pragma unroll
        for (int kic = 0; kic < 8; ++kic) {
          float4 u4 = *(const float4*)(Ud + kic * 4);
          acc[kic * 4 + 0] += wv[dd] * fmaxf(zz[dd] * u4.x + g[kic * 4 + 0], 0.f);
          acc[kic * 4 + 1] += wv[dd] * fmaxf(zz[dd] * u4.y + g[kic * 4 + 1], 0.f);
          acc[kic * 4 + 2] += wv[dd] * fmaxf(zz[dd] * u4.z + g[kic * 4 + 2], 0.f);
          acc[kic * 4 + 3] += wv[dd] * fmaxf(zz[dd] * u4.w + g[kic * 4 + 3], 0.f);
        }
      }
    }
#pragma unroll
    for (int i = 0; i < 8; ++i)
      *(float4*)(sP + bi * 264 + kg * 32 + i * 4) =
          make_float4(acc[i * 4 + 0], acc[i * 4 + 1], acc[i * 4 + 2], acc[i * 4 + 3]);
  }
  __syncthreads();

  // ---- phase 2: acc2[i][c] = sum_k1 P[wg*8+i][k1] * M[h][k1][l+64c]
  const int wg = t >> 6, l = t & 63;
  float acc2[8][4];
#pragma unroll
  for (int i = 0; i < 8; ++i)
#pragma unroll
    for (int c = 0; c < 4; ++c) acc2[i][c] = 0.f;
  const float* Mp = ws_M + h * 65536;
  for (int kc = 0; kc < 64; ++kc) {
    float4 m4[4];
#pragma unroll
    for (int c = 0; c < 4; ++c)
      m4[c] = *(const float4*)(Mp + (l + 64 * c) * 256 + kc * 4);
#pragma unroll
    for (int i = 0; i < 8; ++i) {
      float4 p4 = *(const float4*)(sP + (wg * 8 + i) * 264 + kc * 4);
#pragma unroll
      for (int c = 0; c < 4; ++c)
        acc2[i][c] += p4.x * m4[c].x + p4.y * m4[c].y + p4.z * m4[c].z + p4.w * m4[c].w;
    }
  }

  // ---- phase 3: effect[b, h] via relu + dot with W2o, wave reduction
  float c1r[4], w2r[4];
#pragma unroll
  for (int c = 0; c < 4; ++c) {
    c1r[c] = ws_c1[h * 256 + l + 64 * c];
    w2r[c] = W2o[h * 256 + l + 64 * c];
  }
  const float b2oh = b2o[h];
#pragma unroll
  for (int i = 0; i < 8; ++i) {
    float val = fmaxf(acc2[i][0] + c1r[0], 0.f) * w2r[0]
              + fmaxf(acc2[i][1] + c1r[1], 0.f) * w2r[1]
              + fmaxf(acc2[i][2] + c1r[2], 0.f) * w2r[2]
              + fmaxf(acc2[i][3] + c1r[3], 0.f) * w2r[3];
#pragma unroll
    for (int off = 32; off >= 1; off >>= 1) val += __shfl_xor(val, off, 64);
    if (l == 0) out_eff[(b0 + wg * 8 + i) * 32 + h] = val + b2oh;
  }
}

// ----------------------------------------------------------------
extern "C" void kernel_launch(void* const* d_in, const int* in_sizes, int n_in,
                              void* d_out, int out_size, void* d_ws, size_t ws_size,
                              hipStream_t stream) {
  const float* feat = (const float*)d_in[0];
  const float* act  = (const float*)d_in[1];
  const float* Wq   = (const float*)d_in[2];
  const float* bq   = (const float*)d_in[3];
  const float* Wk   = (const float*)d_in[4];
  const float* bk   = (const float*)d_in[5];
  const float* Wav  = (const float*)d_in[6];
  const float* bav  = (const float*)d_in[7];
  const float* Wfv  = (const float*)d_in[8];
  const float* bfv  = (const float*)d_in[9];
  const float* W1   = (const float*)d_in[10];
  const float* b1   = (const float*)d_in[11];
  const float* W2   = (const float*)d_in[12];
  const float* b2   = (const float*)d_in[13];
  const float* W1o  = (const float*)d_in[14];
  const float* b1o  = (const float*)d_in[15];
  const float* W2o  = (const float*)d_in[16];
  const float* b2o  = (const float*)d_in[17];
  float* out = (float*)d_out;           // [0,16384): effect; [16384,...): attn_weights
  float* ws = (float*)d_ws;             // assumes ws_size >= ~27 MB

  float* ws_w  = ws;                    // 16384
  float* ws_ae = ws + 16384;            // 32768
  float* ws_U  = ws + 49152;            // 262144
  float* ws_c0 = ws + 311296;           // 8192
  float* ws_c1 = ws + 319488;           // 8192
  float* ws_M  = ws + 327680;           // 2097152  (M_T[h][k2][k1])
  float* ws_G  = ws + 2424832;          // 4194304

  hipLaunchKernelGGL(k1_prep, dim3(512), dim3(64), 0, stream,
                     feat, act, Wq, bq, Wk, bk, Wav, bav, ws_w, ws_ae, out + 16384);
  hipLaunchKernelGGL(k2_biases, dim3(32), dim3(256), 0, stream,
                     W1, b1, bfv, W1o, b1o, b2, ws_c0, ws_c1);
  hipLaunchKernelGGL(k3_U, dim3(128), dim3(256), 0, stream, Wfv, W1, ws_U);
  hipLaunchKernelGGL(k4_M, dim3(256), dim3(256), 0, stream, W2, W1o, ws_M);
  hipLaunchKernelGGL(k5_G, dim3(512), dim3(256), 0, stream, W1, ws_ae, ws_c0, ws_G);
  hipLaunchKernelGGL(k6_main, dim3(512), dim3(256), 0, stream,
                     feat, ws_w, ws_U, ws_G, ws_M, ws_c1, W2o, b2o, out);
}

// Round 2
// 261.928 us; speedup vs baseline: 1.3109x; 1.3109x over previous
//
#include <hip/hip_runtime.h>
#include <hip/hip_bf16.h>

// AttnPredictor, restructured (round 2: MFMA phase-2, fused G, 4 kernels):
//   q[b]   = a[b]@Wq + bq ;  ae[b] = a[b]@Wav + bav
//   scores[b,d] = (z[b,d]*(Wk[d]·q[b]) + bk·q[b]) / sqrt(192);  w = softmax_d
//   U[h,d,k]  = Wfv[d,:]·W1[h,0:128,k]          (k3)
//   c0[h,k]   = bfv·W1[h,0:128,k] + b1[h,k]     (k3, dt==4 branch)
//   M_T[h][k2][k1] = (W2[h]@W1o[h])^T  in bf16  (k4)
//   c1[h,k2]  = b2[h]@W1o[h] + b1o[h]           (k4, kt==0)
//   k6: G[b,k] = ae[b]·W1[h,128:192,k] + c0  (LDS)
//       P[b,k] = sum_d w[b,d]*relu(z[b,d]*U[h,d,k] + G[b,k])  -> bf16 LDS
//       effect = relu(P@M + c1)·W2o + b2o   via mfma_f32_16x16x32_bf16

#define B_  512
#define D_  32
#define A_  18
#define VD_ 192
#define HID_ 256
#define H_  32

typedef __attribute__((ext_vector_type(8))) short bf16x8;
typedef __attribute__((ext_vector_type(4))) float f32x4;

__device__ __forceinline__ short f2bf(float x) {
  unsigned u = __float_as_uint(x);
  u += 0x7fffu + ((u >> 16) & 1u);          // round-to-nearest-even
  return (short)(u >> 16);
}

// ---------------------------------------------------------------- K1: q, ae, softmax w, attn_weights out
__global__ __launch_bounds__(64) void k1_prep(
    const float* __restrict__ feat, const float* __restrict__ act,
    const float* __restrict__ Wq, const float* __restrict__ bq,
    const float* __restrict__ Wk, const float* __restrict__ bk,
    const float* __restrict__ Wav, const float* __restrict__ bav,
    float* __restrict__ ws_w, float* __restrict__ ws_ae,
    float* __restrict__ out_aw) {
  const int b = blockIdx.x;
  const int t = threadIdx.x;
  __shared__ float sQ[192];
  __shared__ float sW[32];

  float a_reg[18];
#pragma unroll
  for (int j = 0; j < 18; ++j) a_reg[j] = act[b * 18 + j];

#pragma unroll
  for (int i = 0; i < 3; ++i) {
    const int c = i * 64 + t;
    float acc = bq[c];
#pragma unroll
    for (int j = 0; j < 18; ++j) acc += a_reg[j] * Wq[j * 192 + c];
    sQ[c] = acc;
  }
  {
    float acc = bav[t];
#pragma unroll
    for (int j = 0; j < 18; ++j) acc += a_reg[j] * Wav[j * 64 + t];
    ws_ae[b * 64 + t] = acc;
  }
  __syncthreads();

  float dot = 0.f;
  const float* row = (t < 32) ? (Wk + t * 192) : bk;
  if (t < 33) {
    for (int c4 = 0; c4 < 48; ++c4) {
      float4 r4 = *(const float4*)(row + c4 * 4);
      float4 q4 = *(const float4*)(sQ + c4 * 4);
      dot += r4.x * q4.x + r4.y * q4.y + r4.z * q4.z + r4.w * q4.w;
    }
  }
  const float dotb = __shfl(dot, 32, 64);

  float sc = 0.f;
  if (t < 32) sc = (feat[b * 32 + t] * dot + dotb) * 0.07216878364870322f;
  float mx = sc;
#pragma unroll
  for (int off = 16; off >= 1; off >>= 1) mx = fmaxf(mx, __shfl_xor(mx, off, 32));
  float e = (t < 32) ? __expf(sc - mx) : 0.f;
  float s = e;
#pragma unroll
  for (int off = 16; off >= 1; off >>= 1) s += __shfl_xor(s, off, 32);
  const float w = e / s;
  if (t < 32) { ws_w[b * 32 + t] = w; sW[t] = w; }
  __syncthreads();

#pragma unroll
  for (int i = 0; i < 16; ++i) {
    const int j = i * 64 + t;
    out_aw[b * 1024 + j] = sW[j & 31];
  }
}

// ---------------------------------------------------------------- K3: U[h,d,k] and c0[h,k]
__global__ __launch_bounds__(256) void k3_U(
    const float* __restrict__ Wfv, const float* __restrict__ bfv,
    const float* __restrict__ W1, const float* __restrict__ b1,
    float* __restrict__ ws_U, float* __restrict__ ws_c0) {
  const int bx = blockIdx.x;
  const int h = bx / 5, dt = bx % 5;    // dt 0..3: 8 d's each; dt==4: c0
  const int t = threadIdx.x;
  __shared__ float sF[1024];
  if (dt < 4) {
#pragma unroll
    for (int i = 0; i < 4; ++i) sF[i * 256 + t] = Wfv[dt * 1024 + i * 256 + t];
  } else {
    if (t < 128) sF[t] = bfv[t];
  }
  __syncthreads();

  if (dt < 4) {
    float acc[8];
#pragma unroll
    for (int dd = 0; dd < 8; ++dd) acc[dd] = 0.f;
    for (int fc = 0; fc < 32; ++fc) {
      float w1v[4];
#pragma unroll
      for (int u = 0; u < 4; ++u) w1v[u] = W1[(h * 192 + fc * 4 + u) * 256 + t];
#pragma unroll
      for (int dd = 0; dd < 8; ++dd) {
        float4 f4 = *(const float4*)(sF + dd * 128 + fc * 4);
        acc[dd] += f4.x * w1v[0] + f4.y * w1v[1] + f4.z * w1v[2] + f4.w * w1v[3];
      }
    }
#pragma unroll
    for (int dd = 0; dd < 8; ++dd)
      ws_U[(h * 32 + dt * 8 + dd) * 256 + t] = acc[dd];
  } else {
    float acc = b1[h * 256 + t];
    for (int fc = 0; fc < 32; ++fc) {
      float w1v[4];
#pragma unroll
      for (int u = 0; u < 4; ++u) w1v[u] = W1[(h * 192 + fc * 4 + u) * 256 + t];
      float4 f4 = *(const float4*)(sF + fc * 4);
      acc += f4.x * w1v[0] + f4.y * w1v[1] + f4.z * w1v[2] + f4.w * w1v[3];
    }
    ws_c0[h * 256 + t] = acc;
  }
}

// ---------------------------------------------------------------- K4: M_T[h][k2][k1] (bf16) and c1[h,k2]
__global__ __launch_bounds__(256) void k4_M(
    const float* __restrict__ W2, const float* __restrict__ W1o,
    const float* __restrict__ b2, const float* __restrict__ b1o,
    unsigned short* __restrict__ ws_Mbf, float* __restrict__ ws_c1) {
  const int bx = blockIdx.x;
  const int h = bx >> 3, kt = bx & 7;   // k1 tile of 32
  const int t = threadIdx.x;            // t = k2
  __shared__ float s[8320];
#pragma unroll
  for (int i = 0; i < 24; ++i)
    s[i * 256 + t] = W2[h * 49152 + kt * 6144 + i * 256 + t];
  __syncthreads();
  float acc[32];
#pragma unroll
  for (int r = 0; r < 32; ++r) acc[r] = 0.f;
  float c1acc = 0.f;
  for (int vc = 0; vc < 48; ++vc) {
    float w1o[4], b2v[4];
#pragma unroll
    for (int u = 0; u < 4; ++u) {
      w1o[u] = W1o[(h * 192 + vc * 4 + u) * 256 + t];
      b2v[u] = b2[h * 192 + vc * 4 + u];
    }
    c1acc += b2v[0] * w1o[0] + b2v[1] * w1o[1] + b2v[2] * w1o[2] + b2v[3] * w1o[3];
#pragma unroll
    for (int r = 0; r < 32; ++r) {
      float4 w2 = *(const float4*)(s + r * 192 + vc * 4);
      acc[r] += w2.x * w1o[0] + w2.y * w1o[1] + w2.z * w1o[2] + w2.w * w1o[3];
    }
  }
  if (kt == 0) ws_c1[h * 256 + t] = c1acc + b1o[h * 256 + t];
  __syncthreads();
#pragma unroll
  for (int r = 0; r < 32; ++r) s[r * 260 + t] = acc[r];
  __syncthreads();
  const int k1l = t & 31, k2g = t >> 5;
#pragma unroll
  for (int it = 0; it < 32; ++it) {
    const int k2 = it * 8 + k2g;
    ws_Mbf[(h * 256 + k2) * 256 + kt * 32 + k1l] =
        (unsigned short)f2bf(s[k1l * 260 + k2]);
  }
}

// ---------------------------------------------------------------- K6: G (LDS) -> P (bf16 LDS) -> MFMA P@M -> effect
__global__ __launch_bounds__(256) void k6_main(
    const float* __restrict__ feat, const float* __restrict__ ws_w,
    const float* __restrict__ ws_U, const float* __restrict__ W1,
    const float* __restrict__ ws_ae, const float* __restrict__ ws_c0,
    const unsigned short* __restrict__ ws_Mbf, const float* __restrict__ ws_c1,
    const float* __restrict__ W2o, const float* __restrict__ b2o,
    float* __restrict__ out_eff) {
  const int bx = blockIdx.x;
  const int h = bx >> 4, bt = bx & 15;
  const int b0 = bt * 32;
  const int t = threadIdx.x;

  __shared__ float sG[32 * 260];                 // G[b][k], stride 260 (pad)
  __shared__ __align__(16) char sBuf[32 * 264 * 2];  // sAe (pre) / sP bf16 (main)
  __shared__ float sRed[128];                    // [32 b][4 wave]

  // ---- pre-phase: G[b][k=t] = c0[k] + ae[b]·W1[h,128:192,k]
  {
    float* sAe = (float*)sBuf;                   // [32 b][64 j]
#pragma unroll
    for (int i = 0; i < 8; ++i) sAe[i * 256 + t] = ws_ae[b0 * 64 + i * 256 + t];
    float w1r[64];
#pragma unroll
    for (int j = 0; j < 64; ++j) w1r[j] = W1[(h * 192 + 128 + j) * 256 + t];
    const float c0v = ws_c0[h * 256 + t];
    __syncthreads();
    for (int bi = 0; bi < 32; ++bi) {
      float acc = c0v;
#pragma unroll
      for (int jc = 0; jc < 16; ++jc) {
        float4 a4 = *(const float4*)(sAe + bi * 64 + jc * 4);
        acc += a4.x * w1r[jc * 4 + 0] + a4.y * w1r[jc * 4 + 1]
             + a4.z * w1r[jc * 4 + 2] + a4.w * w1r[jc * 4 + 3];
      }
      sG[bi * 260 + t] = acc;
    }
  }
  __syncthreads();   // sG done; sAe reads done (sBuf reused as sP below)

  // ---- phase 1: P[bi][k] fp32 -> bf16 sP
  {
    const int bi = t >> 3, kg = t & 7;
    const int b = b0 + bi;
    float g[32], acc[32];
#pragma unroll
    for (int i = 0; i < 8; ++i) {
      float4 g4 = *(const float4*)(sG + bi * 260 + kg * 32 + i * 4);
      g[i * 4 + 0] = g4.x; g[i * 4 + 1] = g4.y; g[i * 4 + 2] = g4.z; g[i * 4 + 3] = g4.w;
      acc[i * 4 + 0] = 0.f; acc[i * 4 + 1] = 0.f; acc[i * 4 + 2] = 0.f; acc[i * 4 + 3] = 0.f;
    }
    const float* Up = ws_U + h * 8192 + kg * 32;
    for (int dc = 0; dc < 8; ++dc) {
      float4 z4 = *(const float4*)(feat + b * 32 + dc * 4);
      float4 w4 = *(const float4*)(ws_w + b * 32 + dc * 4);
      float zz[4] = {z4.x, z4.y, z4.z, z4.w};
      float wv[4] = {w4.x, w4.y, w4.z, w4.w};
#pragma unroll
      for (int dd = 0; dd < 4; ++dd) {
        const float* Ud = Up + (dc * 4 + dd) * 256;
#pragma unroll
        for (int kic = 0; kic < 8; ++kic) {
          float4 u4 = *(const float4*)(Ud + kic * 4);
          acc[kic * 4 + 0] += wv[dd] * fmaxf(zz[dd] * u4.x + g[kic * 4 + 0], 0.f);
          acc[kic * 4 + 1] += wv[dd] * fmaxf(zz[dd] * u4.y + g[kic * 4 + 1], 0.f);
          acc[kic * 4 + 2] += wv[dd] * fmaxf(zz[dd] * u4.z + g[kic * 4 + 2], 0.f);
          acc[kic * 4 + 3] += wv[dd] * fmaxf(zz[dd] * u4.w + g[kic * 4 + 3], 0.f);
        }
      }
    }
    short* sP = (short*)sBuf;                    // [32 b][264 k] bf16, pad 8
#pragma unroll
    for (int i = 0; i < 4; ++i) {
      bf16x8 p;
#pragma unroll
      for (int j = 0; j < 8; ++j) p[j] = f2bf(acc[i * 8 + j]);
      *(bf16x8*)(sP + bi * 264 + kg * 32 + i * 8) = p;
    }
  }
  __syncthreads();

  // ---- phase 2: MFMA  D[32 b][64 k2 per wave] = P @ M
  {
    const short* sP = (const short*)sBuf;
    const int wv = t >> 6;                       // wave id: k2 range [wv*64, wv*64+64)
    const int lane = t & 63;
    const int quad = lane >> 4, l15 = lane & 15;

    f32x4 acc[2][4];
    const f32x4 zero = {0.f, 0.f, 0.f, 0.f};
#pragma unroll
    for (int mt = 0; mt < 2; ++mt)
#pragma unroll
      for (int nt = 0; nt < 4; ++nt) acc[mt][nt] = zero;

    float c1r[4], w2r[4];
#pragma unroll
    for (int nt = 0; nt < 4; ++nt) {
      const int col = wv * 64 + nt * 16 + l15;
      c1r[nt] = ws_c1[h * 256 + col];
      w2r[nt] = W2o[h * 256 + col];
    }
    const unsigned short* Mp = ws_Mbf + (size_t)(h * 256 + wv * 64) * 256;

#pragma unroll
    for (int kc = 0; kc < 8; ++kc) {
      bf16x8 a0 = *(const bf16x8*)(sP + l15 * 264 + kc * 32 + quad * 8);
      bf16x8 a1 = *(const bf16x8*)(sP + (16 + l15) * 264 + kc * 32 + quad * 8);
      bf16x8 bf[4];
#pragma unroll
      for (int nt = 0; nt < 4; ++nt)
        bf[nt] = *(const bf16x8*)(Mp + (nt * 16 + l15) * 256 + kc * 32 + quad * 8);
#pragma unroll
      for (int nt = 0; nt < 4; ++nt) {
        acc[0][nt] = __builtin_amdgcn_mfma_f32_16x16x32_bf16(a0, bf[nt], acc[0][nt], 0, 0, 0);
        acc[1][nt] = __builtin_amdgcn_mfma_f32_16x16x32_bf16(a1, bf[nt], acc[1][nt], 0, 0, 0);
      }
    }

    // epilogue: per lane, rows mt*16+quad*4+r, col = wv*64+nt*16+l15
#pragma unroll
    for (int mt = 0; mt < 2; ++mt) {
#pragma unroll
      for (int r = 0; r < 4; ++r) {
        float s = fmaxf(acc[mt][0][r] + c1r[0], 0.f) * w2r[0]
                + fmaxf(acc[mt][1][r] + c1r[1], 0.f) * w2r[1]
                + fmaxf(acc[mt][2][r] + c1r[2], 0.f) * w2r[2]
                + fmaxf(acc[mt][3][r] + c1r[3], 0.f) * w2r[3];
        s += __shfl_xor(s, 1, 64);
        s += __shfl_xor(s, 2, 64);
        s += __shfl_xor(s, 4, 64);
        s += __shfl_xor(s, 8, 64);
        if (l15 == 0) sRed[(mt * 16 + quad * 4 + r) * 4 + wv] = s;
      }
    }
  }
  __syncthreads();
  if (t < 32) {
    float v = sRed[t * 4] + sRed[t * 4 + 1] + sRed[t * 4 + 2] + sRed[t * 4 + 3] + b2o[h];
    out_eff[(b0 + t) * 32 + h] = v;
  }
}

// ----------------------------------------------------------------
extern "C" void kernel_launch(void* const* d_in, const int* in_sizes, int n_in,
                              void* d_out, int out_size, void* d_ws, size_t ws_size,
                              hipStream_t stream) {
  const float* feat = (const float*)d_in[0];
  const float* act  = (const float*)d_in[1];
  const float* Wq   = (const float*)d_in[2];
  const float* bq   = (const float*)d_in[3];
  const float* Wk   = (const float*)d_in[4];
  const float* bk   = (const float*)d_in[5];
  const float* Wav  = (const float*)d_in[6];
  const float* bav  = (const float*)d_in[7];
  const float* Wfv  = (const float*)d_in[8];
  const float* bfv  = (const float*)d_in[9];
  const float* W1   = (const float*)d_in[10];
  const float* b1   = (const float*)d_in[11];
  const float* W2   = (const float*)d_in[12];
  const float* b2   = (const float*)d_in[13];
  const float* W1o  = (const float*)d_in[14];
  const float* b1o  = (const float*)d_in[15];
  const float* W2o  = (const float*)d_in[16];
  const float* b2o  = (const float*)d_in[17];
  float* out = (float*)d_out;           // [0,16384): effect; [16384,...): attn_weights
  float* ws = (float*)d_ws;

  float* ws_w  = ws;                    // 16384
  float* ws_ae = ws + 16384;            // 32768
  float* ws_U  = ws + 49152;            // 262144
  float* ws_c0 = ws + 311296;           // 8192
  float* ws_c1 = ws + 319488;           // 8192
  unsigned short* ws_Mbf = (unsigned short*)(ws + 327680);  // 2M bf16 = 4 MB

  hipLaunchKernelGGL(k1_prep, dim3(512), dim3(64), 0, stream,
                     feat, act, Wq, bq, Wk, bk, Wav, bav, ws_w, ws_ae, out + 16384);
  hipLaunchKernelGGL(k3_U, dim3(160), dim3(256), 0, stream,
                     Wfv, bfv, W1, b1, ws_U, ws_c0);
  hipLaunchKernelGGL(k4_M, dim3(256), dim3(256), 0, stream,
                     W2, W1o, b2, b1o, ws_Mbf, ws_c1);
  hipLaunchKernelGGL(k6_main, dim3(512), dim3(256), 0, stream,
                     feat, ws_w, ws_U, W1, ws_ae, ws_c0, ws_Mbf, ws_c1, W2o, b2o, out);
}

// Round 3
// 199.768 us; speedup vs baseline: 1.7188x; 1.3112x over previous
//
#include <hip/hip_runtime.h>
#include <hip/hip_bf16.h>

// AttnPredictor round 3: 2 launches.
//  kA (960 blocks, range-specialized, all ranges independent):
//   [0,64)    P1: dotk[b,d] = a[b]·Wqk[:,d] + bqk[d]  (Wqk = Wq@Wk^T recomputed per block;
//             bk·q term cancels in softmax) -> w, attn_weights
//   [64,192)  U[h,d,k]  = Wfv[d,:]·W1[h,0:128,k]
//   [192,448) M_T[h][k2][k1] = (W2[h]@W1o[h])^T bf16 ; c1 = b2@W1o + b1o
//   [448,960) G[b,h,k] = ae[b]·W1[h,128:192,k] + c0[h,k]  (ae, c0 recomputed locally)
//  kB (1024 blocks = 32 h x 32 btiles of 16):
//   P[b,k] = sum_d w[b,d]*relu(z[b,d]*U[h,d,k] + G[b,h,k]) -> bf16 LDS
//   effect = relu(P@M + c1)·W2o + b2o  via mfma_f32_16x16x32_bf16

typedef __attribute__((ext_vector_type(8))) short bf16x8;
typedef __attribute__((ext_vector_type(4))) float f32x4;

__device__ __forceinline__ short f2bf(float x) {
  unsigned u = __float_as_uint(x);
  u += 0x7fffu + ((u >> 16) & 1u);          // round-to-nearest-even
  return (short)(u >> 16);
}

__global__ __launch_bounds__(256) void kA_prep(
    const float* __restrict__ feat, const float* __restrict__ act,
    const float* __restrict__ Wq, const float* __restrict__ bq,
    const float* __restrict__ Wk,
    const float* __restrict__ Wav, const float* __restrict__ bav,
    const float* __restrict__ Wfv, const float* __restrict__ bfv,
    const float* __restrict__ W1, const float* __restrict__ b1,
    const float* __restrict__ W2, const float* __restrict__ b2,
    const float* __restrict__ W1o, const float* __restrict__ b1o,
    float* __restrict__ ws_w, float* __restrict__ ws_U,
    unsigned short* __restrict__ ws_Mbf, float* __restrict__ ws_c1,
    float* __restrict__ ws_G, float* __restrict__ out_aw) {
  __shared__ float sh[8448];                // 33 KB, aliased per range
  const int bx = blockIdx.x;
  const int t = threadIdx.x;

  if (bx < 64) {
    // ---------------- P1: softmax weights + attn_weights (8 b per block)
    const int b0 = bx * 8;
    float* sWk = sh;                        // [192 c][32 d] transposed
    float* sA  = sh + 6144;                 // act [8][18]
    float* sQk = sh + 6320;                 // [19 j][32 d] (row 18 = bq row)
    float* sW  = sh + 6944;                 // [8][32]
#pragma unroll
    for (int i = 0; i < 24; ++i) {
      const int idx = i * 256 + t;          // idx = d*192 + c
      sWk[(idx % 192) * 32 + (idx / 192)] = Wk[idx];
    }
    if (t < 144) sA[t] = act[b0 * 18 + t];
    __syncthreads();
    for (int o = t; o < 608; o += 256) {    // Wqk[j][d]; j==18 -> bqk
      const int j = o >> 5, d = o & 31;
      const float* arow = (j < 18) ? (Wq + j * 192) : bq;
      float acc = 0.f;
      for (int c = 0; c < 192; ++c) acc += arow[c] * sWk[c * 32 + d];
      sQk[o] = acc;
    }
    __syncthreads();
    const int bi = t >> 5, d = t & 31;
    float dot = sQk[18 * 32 + d];
#pragma unroll
    for (int j = 0; j < 18; ++j) dot += sA[bi * 18 + j] * sQk[j * 32 + d];
    const float z = feat[b0 * 32 + t];
    float sc = z * dot * 0.07216878364870322f;   // 1/sqrt(192)
    float mx = sc;
#pragma unroll
    for (int off = 16; off >= 1; off >>= 1) mx = fmaxf(mx, __shfl_xor(mx, off, 64));
    const float e = __expf(sc - mx);
    float s = e;
#pragma unroll
    for (int off = 16; off >= 1; off >>= 1) s += __shfl_xor(s, off, 64);
    const float w = e / s;
    ws_w[b0 * 32 + t] = w;
    sW[t] = w;
    __syncthreads();
#pragma unroll
    for (int i = 0; i < 32; ++i)
      out_aw[b0 * 1024 + i * 256 + t] = sW[(i >> 2) * 32 + (t & 31)];

  } else if (bx < 192) {
    // ---------------- U range: 4 blocks per h, 8 d's each
    const int r = bx - 64;
    const int h = r >> 2, dt = r & 3;
    float* sF = sh;                         // [8][128] Wfv tile
#pragma unroll
    for (int i = 0; i < 4; ++i) sF[i * 256 + t] = Wfv[dt * 1024 + i * 256 + t];
    __syncthreads();
    float acc[8];
#pragma unroll
    for (int dd = 0; dd < 8; ++dd) acc[dd] = 0.f;
    for (int fc = 0; fc < 32; ++fc) {
      float w1v[4];
#pragma unroll
      for (int u = 0; u < 4; ++u) w1v[u] = W1[(h * 192 + fc * 4 + u) * 256 + t];
#pragma unroll
      for (int dd = 0; dd < 8; ++dd) {
        float4 f4 = *(const float4*)(sF + dd * 128 + fc * 4);
        acc[dd] += f4.x * w1v[0] + f4.y * w1v[1] + f4.z * w1v[2] + f4.w * w1v[3];
      }
    }
#pragma unroll
    for (int dd = 0; dd < 8; ++dd)
      ws_U[(h * 32 + dt * 8 + dd) * 256 + t] = acc[dd];

  } else if (bx < 448) {
    // ---------------- M range: M_T[h][k2][k1] bf16 + c1
    const int r = bx - 192;
    const int h = r >> 3, kt = r & 7;       // k1 tile of 32
    float* s = sh;
#pragma unroll
    for (int i = 0; i < 24; ++i)
      s[i * 256 + t] = W2[h * 49152 + kt * 6144 + i * 256 + t];
    __syncthreads();
    float acc[32];
#pragma unroll
    for (int rr = 0; rr < 32; ++rr) acc[rr] = 0.f;
    float c1acc = 0.f;
    for (int vc = 0; vc < 48; ++vc) {
      float w1o[4], b2v[4];
#pragma unroll
      for (int u = 0; u < 4; ++u) {
        w1o[u] = W1o[(h * 192 + vc * 4 + u) * 256 + t];
        b2v[u] = b2[h * 192 + vc * 4 + u];
      }
      c1acc += b2v[0] * w1o[0] + b2v[1] * w1o[1] + b2v[2] * w1o[2] + b2v[3] * w1o[3];
#pragma unroll
      for (int rr = 0; rr < 32; ++rr) {
        float4 w2 = *(const float4*)(s + rr * 192 + vc * 4);
        acc[rr] += w2.x * w1o[0] + w2.y * w1o[1] + w2.z * w1o[2] + w2.w * w1o[3];
      }
    }
    if (kt == 0) ws_c1[h * 256 + t] = c1acc + b1o[h * 256 + t];
    __syncthreads();
#pragma unroll
    for (int rr = 0; rr < 32; ++rr) s[rr * 260 + t] = acc[rr];
    __syncthreads();
    const int k1l = t & 31, k2g = t >> 5;
#pragma unroll
    for (int it = 0; it < 32; ++it) {
      const int k2 = it * 8 + k2g;
      ws_Mbf[(h * 256 + k2) * 256 + kt * 32 + k1l] =
          (unsigned short)f2bf(s[k1l * 260 + k2]);
    }

  } else {
    // ---------------- G range: 16 blocks per h, 32 b each; ae & c0 local
    const int r = bx - 448;
    const int h = r >> 4, bt = r & 15;
    const int b0 = bt * 32;
    float* sA  = sh;                        // act [32][18]
    float* sAe = sh + 576;                  // [32][64]
    for (int i = t; i < 576; i += 256) sA[i] = act[b0 * 18 + i];
    __syncthreads();
    for (int o = t; o < 2048; o += 256) {
      const int bi = o >> 6, j = o & 63;
      float acc = bav[j];
#pragma unroll
      for (int jj = 0; jj < 18; ++jj) acc += sA[bi * 18 + jj] * Wav[jj * 64 + j];
      sAe[o] = acc;
    }
    float c0 = b1[h * 256 + t];
    for (int f = 0; f < 128; ++f) c0 += bfv[f] * W1[(h * 192 + f) * 256 + t];
    float w1r[64];
#pragma unroll
    for (int j = 0; j < 64; ++j) w1r[j] = W1[(h * 192 + 128 + j) * 256 + t];
    __syncthreads();
    for (int bi = 0; bi < 32; ++bi) {
      float acc = c0;
#pragma unroll
      for (int jc = 0; jc < 16; ++jc) {
        float4 a4 = *(const float4*)(sAe + bi * 64 + jc * 4);
        acc += a4.x * w1r[jc * 4 + 0] + a4.y * w1r[jc * 4 + 1]
             + a4.z * w1r[jc * 4 + 2] + a4.w * w1r[jc * 4 + 3];
      }
      ws_G[(b0 + bi) * 8192 + h * 256 + t] = acc;
    }
  }
}

// ---------------------------------------------------------------- kB: P + MFMA P@M + effect
__global__ __launch_bounds__(256) void kB_main(
    const float* __restrict__ feat, const float* __restrict__ ws_w,
    const float* __restrict__ ws_U, const float* __restrict__ ws_G,
    const unsigned short* __restrict__ ws_Mbf, const float* __restrict__ ws_c1,
    const float* __restrict__ W2o, const float* __restrict__ b2o,
    float* __restrict__ out_eff) {
  const int bx = blockIdx.x;
  const int h = bx >> 5, bt = bx & 31;      // 16 b per block
  const int b0 = bt * 16;
  const int t = threadIdx.x;
  __shared__ __align__(16) short sP[16 * 264];
  __shared__ float sRed[64];                // [16 b][4 wave]

  // ---- phase 1: P[bi][16 k's] per thread -> bf16 LDS
  {
    const int bi = t >> 4, kg = t & 15;
    const int b = b0 + bi;
    float g[16], acc[16];
    const float* Gp = ws_G + b * 8192 + h * 256 + kg * 16;
#pragma unroll
    for (int i = 0; i < 4; ++i) {
      float4 g4 = *(const float4*)(Gp + i * 4);
      g[i * 4 + 0] = g4.x; g[i * 4 + 1] = g4.y; g[i * 4 + 2] = g4.z; g[i * 4 + 3] = g4.w;
      acc[i * 4 + 0] = 0.f; acc[i * 4 + 1] = 0.f; acc[i * 4 + 2] = 0.f; acc[i * 4 + 3] = 0.f;
    }
    const float* Up = ws_U + h * 8192 + kg * 16;
    for (int dc = 0; dc < 8; ++dc) {
      float4 z4 = *(const float4*)(feat + b * 32 + dc * 4);
      float4 w4 = *(const float4*)(ws_w + b * 32 + dc * 4);
      float zz[4] = {z4.x, z4.y, z4.z, z4.w};
      float wv[4] = {w4.x, w4.y, w4.z, w4.w};
#pragma unroll
      for (int dd = 0; dd < 4; ++dd) {
        const float* Ud = Up + (dc * 4 + dd) * 256;
#pragma unroll
        for (int kic = 0; kic < 4; ++kic) {
          float4 u4 = *(const float4*)(Ud + kic * 4);
          acc[kic * 4 + 0] += wv[dd] * fmaxf(zz[dd] * u4.x + g[kic * 4 + 0], 0.f);
          acc[kic * 4 + 1] += wv[dd] * fmaxf(zz[dd] * u4.y + g[kic * 4 + 1], 0.f);
          acc[kic * 4 + 2] += wv[dd] * fmaxf(zz[dd] * u4.z + g[kic * 4 + 2], 0.f);
          acc[kic * 4 + 3] += wv[dd] * fmaxf(zz[dd] * u4.w + g[kic * 4 + 3], 0.f);
        }
      }
    }
#pragma unroll
    for (int i = 0; i < 2; ++i) {
      bf16x8 p;
#pragma unroll
      for (int j = 0; j < 8; ++j) p[j] = f2bf(acc[i * 8 + j]);
      *(bf16x8*)(sP + bi * 264 + kg * 16 + i * 8) = p;
    }
  }
  __syncthreads();

  // ---- phase 2: D[16 b][64 k2 per wave] = P @ M ; epilogue
  {
    const int wv = t >> 6;
    const int lane = t & 63;
    const int quad = lane >> 4, l15 = lane & 15;

    f32x4 acc[4];
    const f32x4 zero = {0.f, 0.f, 0.f, 0.f};
#pragma unroll
    for (int nt = 0; nt < 4; ++nt) acc[nt] = zero;

    float c1r[4], w2r[4];
#pragma unroll
    for (int nt = 0; nt < 4; ++nt) {
      const int col = wv * 64 + nt * 16 + l15;
      c1r[nt] = ws_c1[h * 256 + col];
      w2r[nt] = W2o[h * 256 + col];
    }
    const unsigned short* Mp = ws_Mbf + (size_t)(h * 256 + wv * 64) * 256;

#pragma unroll
    for (int kc = 0; kc < 8; ++kc) {
      bf16x8 a0 = *(const bf16x8*)(sP + l15 * 264 + kc * 32 + quad * 8);
      bf16x8 bfr[4];
#pragma unroll
      for (int nt = 0; nt < 4; ++nt)
        bfr[nt] = *(const bf16x8*)(Mp + (nt * 16 + l15) * 256 + kc * 32 + quad * 8);
#pragma unroll
      for (int nt = 0; nt < 4; ++nt)
        acc[nt] = __builtin_amdgcn_mfma_f32_16x16x32_bf16(a0, bfr[nt], acc[nt], 0, 0, 0);
    }
#pragma unroll
    for (int r = 0; r < 4; ++r) {
      float s = fmaxf(acc[0][r] + c1r[0], 0.f) * w2r[0]
              + fmaxf(acc[1][r] + c1r[1], 0.f) * w2r[1]
              + fmaxf(acc[2][r] + c1r[2], 0.f) * w2r[2]
              + fmaxf(acc[3][r] + c1r[3], 0.f) * w2r[3];
      s += __shfl_xor(s, 1, 64);
      s += __shfl_xor(s, 2, 64);
      s += __shfl_xor(s, 4, 64);
      s += __shfl_xor(s, 8, 64);
      if (l15 == 0) sRed[(quad * 4 + r) * 4 + wv] = s;
    }
  }
  __syncthreads();
  if (t < 16) {
    float v = sRed[t * 4] + sRed[t * 4 + 1] + sRed[t * 4 + 2] + sRed[t * 4 + 3] + b2o[h];
    out_eff[(b0 + t) * 32 + h] = v;
  }
}

// ----------------------------------------------------------------
extern "C" void kernel_launch(void* const* d_in, const int* in_sizes, int n_in,
                              void* d_out, int out_size, void* d_ws, size_t ws_size,
                              hipStream_t stream) {
  const float* feat = (const float*)d_in[0];
  const float* act  = (const float*)d_in[1];
  const float* Wq   = (const float*)d_in[2];
  const float* bq   = (const float*)d_in[3];
  const float* Wk   = (const float*)d_in[4];
  // d_in[5] = bk: cancels in softmax
  const float* Wav  = (const float*)d_in[6];
  const float* bav  = (const float*)d_in[7];
  const float* Wfv  = (const float*)d_in[8];
  const float* bfv  = (const float*)d_in[9];
  const float* W1   = (const float*)d_in[10];
  const float* b1   = (const float*)d_in[11];
  const float* W2   = (const float*)d_in[12];
  const float* b2   = (const float*)d_in[13];
  const float* W1o  = (const float*)d_in[14];
  const float* b1o  = (const float*)d_in[15];
  const float* W2o  = (const float*)d_in[16];
  const float* b2o  = (const float*)d_in[17];
  float* out = (float*)d_out;               // [0,16384): effect; rest: attn_weights
  float* ws = (float*)d_ws;

  float* ws_w  = ws;                                        // 16384
  float* ws_U  = ws + 16384;                                // 262144
  float* ws_c1 = ws + 278528;                               // 8192
  unsigned short* ws_Mbf = (unsigned short*)(ws + 286720);  // 2097152 shorts
  float* ws_G  = ws + 1335296;                              // 4194304

  hipLaunchKernelGGL(kA_prep, dim3(960), dim3(256), 0, stream,
                     feat, act, Wq, bq, Wk, Wav, bav, Wfv, bfv, W1, b1,
                     W2, b2, W1o, b1o, ws_w, ws_U, ws_Mbf, ws_c1, ws_G,
                     out + 16384);
  hipLaunchKernelGGL(kB_main, dim3(1024), dim3(256), 0, stream,
                     feat, ws_w, ws_U, ws_G, ws_Mbf, ws_c1, W2o, b2o, out);
}

// Round 4
// 177.880 us; speedup vs baseline: 1.9303x; 1.1230x over previous
//
#include <hip/hip_runtime.h>
#include <hip/hip_bf16.h>

// AttnPredictor round 4: 3 launches (kA -> kG -> kB).
//  kA (736 blocks, range-specialized):
//   [0,64)    P1: w = softmax_d(z*(a@Wqk + bqk)/sqrt192), attn_weights, ae = a@Wav+bav
//   [64,224)  U[h,d,k] = Wfv[d,:]·W1[h,0:128,k] ; dt==4 block: c0 = bfv·W1[h,0:128]+b1
//   [224,736) M_T[h][k2][k1] = (W2[h]@W1o[h])^T bf16 (16 blocks/h); c1 = b2@W1o+b1o
//  kG (512 blocks): G[b,h,k] = ae[b]·W1[h,128:192,k] + c0[h,k]   (reads ws_ae, ws_c0)
//  kB (1024 blocks, XCD-swizzled): P = sum_d w_d*relu(z_d*U + G) -> bf16 LDS;
//   effect = relu(P@M + c1)·W2o + b2o via mfma_f32_16x16x32_bf16

typedef __attribute__((ext_vector_type(8))) short bf16x8;
typedef __attribute__((ext_vector_type(4))) short bf16x4;
typedef __attribute__((ext_vector_type(4))) float f32x4;

__device__ __forceinline__ short f2bf(float x) {
  unsigned u = __float_as_uint(x);
  u += 0x7fffu + ((u >> 16) & 1u);          // round-to-nearest-even
  return (short)(u >> 16);
}

__global__ __launch_bounds__(256) void kA_prep(
    const float* __restrict__ feat, const float* __restrict__ act,
    const float* __restrict__ Wq, const float* __restrict__ bq,
    const float* __restrict__ Wk,
    const float* __restrict__ Wav, const float* __restrict__ bav,
    const float* __restrict__ Wfv, const float* __restrict__ bfv,
    const float* __restrict__ W1, const float* __restrict__ b1,
    const float* __restrict__ W2, const float* __restrict__ b2,
    const float* __restrict__ W1o, const float* __restrict__ b1o,
    float* __restrict__ ws_w, float* __restrict__ ws_ae,
    float* __restrict__ ws_U, float* __restrict__ ws_c0,
    unsigned short* __restrict__ ws_Mbf, float* __restrict__ ws_c1,
    float* __restrict__ out_aw) {
  __shared__ float sh[8448];                // 33 KB, aliased per range
  const int bx = blockIdx.x;
  const int t = threadIdx.x;

  if (bx < 64) {
    // ---------------- P1: softmax weights + attn_weights + ae (8 b per block)
    const int b0 = bx * 8;
    float* sWk = sh;                        // [192 c][32 d] transposed
    float* sA  = sh + 6144;                 // act [8][18]
    float* sQk = sh + 6320;                 // [19 j][32 d] (row 18 = bq row)
    float* sW  = sh + 6944;                 // [8][32]
#pragma unroll
    for (int i = 0; i < 24; ++i) {
      const int idx = i * 256 + t;          // idx = d*192 + c
      sWk[(idx % 192) * 32 + (idx / 192)] = Wk[idx];
    }
    if (t < 144) sA[t] = act[b0 * 18 + t];
    __syncthreads();
    for (int o = t; o < 608; o += 256) {    // Wqk[j][d]; j==18 -> bqk
      const int j = o >> 5, d = o & 31;
      const float* arow = (j < 18) ? (Wq + j * 192) : bq;
      float acc = 0.f;
      for (int c = 0; c < 192; ++c) acc += arow[c] * sWk[c * 32 + d];
      sQk[o] = acc;
    }
    __syncthreads();
    {
      const int bi = t >> 5, d = t & 31;
      float dot = sQk[18 * 32 + d];
#pragma unroll
      for (int j = 0; j < 18; ++j) dot += sA[bi * 18 + j] * sQk[j * 32 + d];
      const float z = feat[b0 * 32 + t];
      float sc = z * dot * 0.07216878364870322f;   // 1/sqrt(192)
      float mx = sc;
#pragma unroll
      for (int off = 16; off >= 1; off >>= 1) mx = fmaxf(mx, __shfl_xor(mx, off, 64));
      const float e = __expf(sc - mx);
      float s = e;
#pragma unroll
      for (int off = 16; off >= 1; off >>= 1) s += __shfl_xor(s, off, 64);
      const float w = e / s;
      ws_w[b0 * 32 + t] = w;
      sW[t] = w;
    }
    // ae = a@Wav + bav  (sA still live)
#pragma unroll
    for (int o = t; o < 512; o += 256) {
      const int bi = o >> 6, j = o & 63;
      float acc = bav[j];
#pragma unroll
      for (int jj = 0; jj < 18; ++jj) acc += sA[bi * 18 + jj] * Wav[jj * 64 + j];
      ws_ae[b0 * 64 + o] = acc;
    }
    __syncthreads();
#pragma unroll
    for (int i = 0; i < 32; ++i)
      out_aw[b0 * 1024 + i * 256 + t] = sW[(i >> 2) * 32 + (t & 31)];

  } else if (bx < 224) {
    // ---------------- U range: 5 blocks per h (dt<4: 8 d's; dt==4: c0)
    const int r = bx - 64;
    const int h = r / 5, dt = r % 5;
    float* sF = sh;                         // [8][128] Wfv tile (or bfv)
    if (dt < 4) {
#pragma unroll
      for (int i = 0; i < 4; ++i) sF[i * 256 + t] = Wfv[dt * 1024 + i * 256 + t];
    } else {
      if (t < 128) sF[t] = bfv[t];
    }
    __syncthreads();
    if (dt < 4) {
      float acc[8];
#pragma unroll
      for (int dd = 0; dd < 8; ++dd) acc[dd] = 0.f;
      for (int fc = 0; fc < 32; ++fc) {
        float w1v[4];
#pragma unroll
        for (int u = 0; u < 4; ++u) w1v[u] = W1[(h * 192 + fc * 4 + u) * 256 + t];
#pragma unroll
        for (int dd = 0; dd < 8; ++dd) {
          float4 f4 = *(const float4*)(sF + dd * 128 + fc * 4);
          acc[dd] += f4.x * w1v[0] + f4.y * w1v[1] + f4.z * w1v[2] + f4.w * w1v[3];
        }
      }
#pragma unroll
      for (int dd = 0; dd < 8; ++dd)
        ws_U[(h * 32 + dt * 8 + dd) * 256 + t] = acc[dd];
    } else {
      float acc = b1[h * 256 + t];
      for (int fc = 0; fc < 32; ++fc) {
        float w1v[4];
#pragma unroll
        for (int u = 0; u < 4; ++u) w1v[u] = W1[(h * 192 + fc * 4 + u) * 256 + t];
        float4 f4 = *(const float4*)(sF + fc * 4);
        acc += f4.x * w1v[0] + f4.y * w1v[1] + f4.z * w1v[2] + f4.w * w1v[3];
      }
      ws_c0[h * 256 + t] = acc;
    }

  } else {
    // ---------------- M range: 16 blocks/h, 16 k1-rows each
    const int r = bx - 224;
    const int h = r >> 4, kt = r & 15;
    float* s = sh;
#pragma unroll
    for (int i = 0; i < 12; ++i)
      s[i * 256 + t] = W2[h * 49152 + kt * 3072 + i * 256 + t];
    __syncthreads();
    float acc[16];
#pragma unroll
    for (int rr = 0; rr < 16; ++rr) acc[rr] = 0.f;
    float c1acc = 0.f;
    for (int vc = 0; vc < 48; ++vc) {
      float w1o[4], b2v[4];
#pragma unroll
      for (int u = 0; u < 4; ++u) {
        w1o[u] = W1o[(h * 192 + vc * 4 + u) * 256 + t];
        b2v[u] = b2[h * 192 + vc * 4 + u];
      }
      c1acc += b2v[0] * w1o[0] + b2v[1] * w1o[1] + b2v[2] * w1o[2] + b2v[3] * w1o[3];
#pragma unroll
      for (int rr = 0; rr < 16; ++rr) {
        float4 w2 = *(const float4*)(s + rr * 192 + vc * 4);
        acc[rr] += w2.x * w1o[0] + w2.y * w1o[1] + w2.z * w1o[2] + w2.w * w1o[3];
      }
    }
    if (kt == 0) ws_c1[h * 256 + t] = c1acc + b1o[h * 256 + t];
    __syncthreads();
#pragma unroll
    for (int rr = 0; rr < 16; ++rr) s[rr * 260 + t] = acc[rr];
    __syncthreads();
    const int k1l = t & 15, k2g = t >> 4;
#pragma unroll
    for (int it = 0; it < 16; ++it) {
      const int k2 = it * 16 + k2g;
      ws_Mbf[(h * 256 + k2) * 256 + kt * 16 + k1l] =
          (unsigned short)f2bf(s[k1l * 260 + k2]);
    }
  }
}

// ---------------------------------------------------------------- kG: G[b,h,k]
__global__ __launch_bounds__(256) void kG_G(
    const float* __restrict__ W1, const float* __restrict__ ws_ae,
    const float* __restrict__ ws_c0, float* __restrict__ ws_G) {
  const int bx = blockIdx.x;
  const int h = bx >> 4, bt = bx & 15;
  const int b0 = bt * 32;
  const int t = threadIdx.x;
  __shared__ float sAe[2048];               // [32 b][64 j]
#pragma unroll
  for (int i = 0; i < 8; ++i) sAe[i * 256 + t] = ws_ae[b0 * 64 + i * 256 + t];
  float w1r[64];
#pragma unroll
  for (int j = 0; j < 64; ++j) w1r[j] = W1[(h * 192 + 128 + j) * 256 + t];
  const float c0v = ws_c0[h * 256 + t];
  __syncthreads();
  for (int bi = 0; bi < 32; ++bi) {
    float acc = c0v;
#pragma unroll
    for (int jc = 0; jc < 16; ++jc) {
      float4 a4 = *(const float4*)(sAe + bi * 64 + jc * 4);
      acc += a4.x * w1r[jc * 4 + 0] + a4.y * w1r[jc * 4 + 1]
           + a4.z * w1r[jc * 4 + 2] + a4.w * w1r[jc * 4 + 3];
    }
    ws_G[(b0 + bi) * 8192 + h * 256 + t] = acc;
  }
}

// ---------------------------------------------------------------- kB: P + MFMA P@M + effect
__global__ __launch_bounds__(256) void kB_main(
    const float* __restrict__ feat, const float* __restrict__ ws_w,
    const float* __restrict__ ws_U, const float* __restrict__ ws_G,
    const unsigned short* __restrict__ ws_Mbf, const float* __restrict__ ws_c1,
    const float* __restrict__ W2o, const float* __restrict__ b2o,
    float* __restrict__ out_eff) {
  const int bx = blockIdx.x;
  // XCD swizzle: consecutive bx round-robin XCDs; give each XCD a 4-h slice.
  const int h = (bx & 7) * 4 + ((bx >> 3) & 3);
  const int bt = bx >> 5;                   // 16 b per block
  const int b0 = bt * 16;
  const int t = threadIdx.x;
  __shared__ __align__(16) short sP[16 * 264];
  __shared__ float sRed[64];                // [16 b][4 wave]

  // ---- phase 1: P for thread's (bi = t>>4, k in {seg*64 + kg*4 + c})
  {
    const int bi = t >> 4, kg = t & 15;
    const int b = b0 + bi;
    float g[16], acc[16];
    const float* Gp = ws_G + b * 8192 + h * 256 + kg * 4;
#pragma unroll
    for (int seg = 0; seg < 4; ++seg) {
      float4 g4 = *(const float4*)(Gp + seg * 64);
      g[seg * 4 + 0] = g4.x; g[seg * 4 + 1] = g4.y;
      g[seg * 4 + 2] = g4.z; g[seg * 4 + 3] = g4.w;
      acc[seg * 4 + 0] = 0.f; acc[seg * 4 + 1] = 0.f;
      acc[seg * 4 + 2] = 0.f; acc[seg * 4 + 3] = 0.f;
    }
    const float* Up = ws_U + h * 8192 + kg * 4;
    for (int dc = 0; dc < 8; ++dc) {
      float4 z4 = *(const float4*)(feat + b * 32 + dc * 4);
      float4 w4 = *(const float4*)(ws_w + b * 32 + dc * 4);
      float zz[4] = {z4.x, z4.y, z4.z, z4.w};
      float wv[4] = {w4.x, w4.y, w4.z, w4.w};
#pragma unroll
      for (int dd = 0; dd < 4; ++dd) {
        const float* Ud = Up + (dc * 4 + dd) * 256;
#pragma unroll
        for (int seg = 0; seg < 4; ++seg) {
          float4 u4 = *(const float4*)(Ud + seg * 64);
          acc[seg * 4 + 0] += wv[dd] * fmaxf(zz[dd] * u4.x + g[seg * 4 + 0], 0.f);
          acc[seg * 4 + 1] += wv[dd] * fmaxf(zz[dd] * u4.y + g[seg * 4 + 1], 0.f);
          acc[seg * 4 + 2] += wv[dd] * fmaxf(zz[dd] * u4.z + g[seg * 4 + 2], 0.f);
          acc[seg * 4 + 3] += wv[dd] * fmaxf(zz[dd] * u4.w + g[seg * 4 + 3], 0.f);
        }
      }
    }
#pragma unroll
    for (int seg = 0; seg < 4; ++seg) {
      bf16x4 p;
#pragma unroll
      for (int j = 0; j < 4; ++j) p[j] = f2bf(acc[seg * 4 + j]);
      *(bf16x4*)(sP + bi * 264 + seg * 64 + kg * 4) = p;
    }
  }
  __syncthreads();

  // ---- phase 2: D[16 b][64 k2 per wave] = P @ M ; epilogue
  {
    const int wv = t >> 6;
    const int lane = t & 63;
    const int quad = lane >> 4, l15 = lane & 15;

    f32x4 acc[4];
    const f32x4 zero = {0.f, 0.f, 0.f, 0.f};
#pragma unroll
    for (int nt = 0; nt < 4; ++nt) acc[nt] = zero;

    float c1r[4], w2r[4];
#pragma unroll
    for (int nt = 0; nt < 4; ++nt) {
      const int col = wv * 64 + nt * 16 + l15;
      c1r[nt] = ws_c1[h * 256 + col];
      w2r[nt] = W2o[h * 256 + col];
    }
    const unsigned short* Mp = ws_Mbf + (size_t)(h * 256 + wv * 64) * 256;

#pragma unroll
    for (int kc = 0; kc < 8; ++kc) {
      bf16x8 a0 = *(const bf16x8*)(sP + l15 * 264 + kc * 32 + quad * 8);
      bf16x8 bfr[4];
#pragma unroll
      for (int nt = 0; nt < 4; ++nt)
        bfr[nt] = *(const bf16x8*)(Mp + (nt * 16 + l15) * 256 + kc * 32 + quad * 8);
#pragma unroll
      for (int nt = 0; nt < 4; ++nt)
        acc[nt] = __builtin_amdgcn_mfma_f32_16x16x32_bf16(a0, bfr[nt], acc[nt], 0, 0, 0);
    }
#pragma unroll
    for (int r = 0; r < 4; ++r) {
      float s = fmaxf(acc[0][r] + c1r[0], 0.f) * w2r[0]
              + fmaxf(acc[1][r] + c1r[1], 0.f) * w2r[1]
              + fmaxf(acc[2][r] + c1r[2], 0.f) * w2r[2]
              + fmaxf(acc[3][r] + c1r[3], 0.f) * w2r[3];
      s += __shfl_xor(s, 1, 64);
      s += __shfl_xor(s, 2, 64);
      s += __shfl_xor(s, 4, 64);
      s += __shfl_xor(s, 8, 64);
      if (l15 == 0) sRed[(quad * 4 + r) * 4 + wv] = s;
    }
  }
  __syncthreads();
  if (t < 16) {
    float v = sRed[t * 4] + sRed[t * 4 + 1] + sRed[t * 4 + 2] + sRed[t * 4 + 3] + b2o[h];
    out_eff[(b0 + t) * 32 + h] = v;
  }
}

// ----------------------------------------------------------------
extern "C" void kernel_launch(void* const* d_in, const int* in_sizes, int n_in,
                              void* d_out, int out_size, void* d_ws, size_t ws_size,
                              hipStream_t stream) {
  const float* feat = (const float*)d_in[0];
  const float* act  = (const float*)d_in[1];
  const float* Wq   = (const float*)d_in[2];
  const float* bq   = (const float*)d_in[3];
  const float* Wk   = (const float*)d_in[4];
  // d_in[5] = bk: cancels in softmax
  const float* Wav  = (const float*)d_in[6];
  const float* bav  = (const float*)d_in[7];
  const float* Wfv  = (const float*)d_in[8];
  const float* bfv  = (const float*)d_in[9];
  const float* W1   = (const float*)d_in[10];
  const float* b1   = (const float*)d_in[11];
  const float* W2   = (const float*)d_in[12];
  const float* b2   = (const float*)d_in[13];
  const float* W1o  = (const float*)d_in[14];
  const float* b1o  = (const float*)d_in[15];
  const float* W2o  = (const float*)d_in[16];
  const float* b2o  = (const float*)d_in[17];
  float* out = (float*)d_out;               // [0,16384): effect; rest: attn_weights
  float* ws = (float*)d_ws;

  float* ws_w  = ws;                                        // 16384
  float* ws_ae = ws + 16384;                                // 32768
  float* ws_U  = ws + 49152;                                // 262144
  float* ws_c0 = ws + 311296;                               // 8192
  float* ws_c1 = ws + 319488;                               // 8192
  unsigned short* ws_Mbf = (unsigned short*)(ws + 327680);  // 2097152 shorts
  float* ws_G  = ws + 1376256;                              // 4194304

  hipLaunchKernelGGL(kA_prep, dim3(736), dim3(256), 0, stream,
                     feat, act, Wq, bq, Wk, Wav, bav, Wfv, bfv, W1, b1,
                     W2, b2, W1o, b1o, ws_w, ws_ae, ws_U, ws_c0, ws_Mbf, ws_c1,
                     out + 16384);
  hipLaunchKernelGGL(kG_G, dim3(512), dim3(256), 0, stream,
                     W1, ws_ae, ws_c0, ws_G);
  hipLaunchKernelGGL(kB_main, dim3(1024), dim3(256), 0, stream,
                     feat, ws_w, ws_U, ws_G, ws_Mbf, ws_c1, W2o, b2o, out);
}

// Round 6
// 168.907 us; speedup vs baseline: 2.0328x; 1.0531x over previous
//
#include <hip/hip_runtime.h>
#include <hip/hip_bf16.h>

// AttnPredictor round 6: 2 plain dispatches (kA -> kB). Round-4 kA verbatim;
// kB fuses the G computation (round-4 kG) as an LDS pre-phase.
//  kA (736 blocks, range-specialized):
//   [0,64)    P1: w = softmax_d(z*(a@Wqk + bqk)/sqrt192) (bk·q cancels),
//             attn_weights, ae = a@Wav + bav
//   [64,224)  U[h,d,k] = Wfv[d,:]·W1[h,0:128,k] ; dt==4: c0 = bfv·W1[h,0:128]+b1
//   [224,736) M_T[h][k2][k1] = (W2[h]@W1o[h])^T bf16 (16 blocks/h); c1 = b2@W1o+b1o
//  kB (1024 blocks, XCD-swizzled h, 16 b per block):
//   G[bi][k] = ae·W1[h,128:192,k] + c0      (LDS)
//   P[bi][k] = sum_d w_d*relu(z_d*U + G)    (bf16 LDS)
//   effect   = relu(P@M + c1)·W2o + b2o     via mfma_f32_16x16x32_bf16

typedef __attribute__((ext_vector_type(8))) short bf16x8;
typedef __attribute__((ext_vector_type(4))) short bf16x4;
typedef __attribute__((ext_vector_type(4))) float f32x4;

__device__ __forceinline__ short f2bf(float x) {
  unsigned u = __float_as_uint(x);
  u += 0x7fffu + ((u >> 16) & 1u);          // round-to-nearest-even
  return (short)(u >> 16);
}

__global__ __launch_bounds__(256) void kA_prep(
    const float* __restrict__ feat, const float* __restrict__ act,
    const float* __restrict__ Wq, const float* __restrict__ bq,
    const float* __restrict__ Wk,
    const float* __restrict__ Wav, const float* __restrict__ bav,
    const float* __restrict__ Wfv, const float* __restrict__ bfv,
    const float* __restrict__ W1, const float* __restrict__ b1,
    const float* __restrict__ W2, const float* __restrict__ b2,
    const float* __restrict__ W1o, const float* __restrict__ b1o,
    float* __restrict__ ws_w, float* __restrict__ ws_ae,
    float* __restrict__ ws_U, float* __restrict__ ws_c0,
    unsigned short* __restrict__ ws_Mbf, float* __restrict__ ws_c1,
    float* __restrict__ out_aw) {
  __shared__ float sh[8448];                // 33 KB, aliased per range
  const int bx = blockIdx.x;
  const int t = threadIdx.x;

  if (bx < 64) {
    // ---------------- P1: softmax weights + attn_weights + ae (8 b per block)
    const int b0 = bx * 8;
    float* sWk = sh;                        // [192 c][32 d] transposed
    float* sA  = sh + 6144;                 // act [8][18]
    float* sQk = sh + 6320;                 // [19 j][32 d] (row 18 = bq row)
    float* sW  = sh + 6944;                 // [8][32]
#pragma unroll
    for (int i = 0; i < 24; ++i) {
      const int idx = i * 256 + t;          // idx = d*192 + c
      sWk[(idx % 192) * 32 + (idx / 192)] = Wk[idx];
    }
    if (t < 144) sA[t] = act[b0 * 18 + t];
    __syncthreads();
    for (int o = t; o < 608; o += 256) {    // Wqk[j][d]; j==18 -> bqk
      const int j = o >> 5, d = o & 31;
      const float* arow = (j < 18) ? (Wq + j * 192) : bq;
      float acc = 0.f;
      for (int c = 0; c < 192; ++c) acc += arow[c] * sWk[c * 32 + d];
      sQk[o] = acc;
    }
    __syncthreads();
    {
      const int bi = t >> 5, d = t & 31;
      float dot = sQk[18 * 32 + d];
#pragma unroll
      for (int j = 0; j < 18; ++j) dot += sA[bi * 18 + j] * sQk[j * 32 + d];
      const float z = feat[b0 * 32 + t];
      float sc = z * dot * 0.07216878364870322f;   // 1/sqrt(192)
      float mx = sc;
#pragma unroll
      for (int off = 16; off >= 1; off >>= 1) mx = fmaxf(mx, __shfl_xor(mx, off, 64));
      const float e = __expf(sc - mx);
      float s = e;
#pragma unroll
      for (int off = 16; off >= 1; off >>= 1) s += __shfl_xor(s, off, 64);
      const float w = e / s;
      ws_w[b0 * 32 + t] = w;
      sW[t] = w;
    }
#pragma unroll
    for (int o = t; o < 512; o += 256) {    // ae = a@Wav + bav
      const int bi = o >> 6, j = o & 63;
      float acc = bav[j];
#pragma unroll
      for (int jj = 0; jj < 18; ++jj) acc += sA[bi * 18 + jj] * Wav[jj * 64 + j];
      ws_ae[b0 * 64 + o] = acc;
    }
    __syncthreads();
#pragma unroll
    for (int i = 0; i < 32; ++i)
      out_aw[b0 * 1024 + i * 256 + t] = sW[(i >> 2) * 32 + (t & 31)];

  } else if (bx < 224) {
    // ---------------- U range: 5 blocks per h (dt<4: 8 d's; dt==4: c0)
    const int r = bx - 64;
    const int h = r / 5, dt = r % 5;
    float* sF = sh;                         // [8][128] Wfv tile (or bfv)
    if (dt < 4) {
#pragma unroll
      for (int i = 0; i < 4; ++i) sF[i * 256 + t] = Wfv[dt * 1024 + i * 256 + t];
    } else {
      if (t < 128) sF[t] = bfv[t];
    }
    __syncthreads();
    if (dt < 4) {
      float acc[8];
#pragma unroll
      for (int dd = 0; dd < 8; ++dd) acc[dd] = 0.f;
      for (int fc = 0; fc < 32; ++fc) {
        float w1v[4];
#pragma unroll
        for (int u = 0; u < 4; ++u) w1v[u] = W1[(h * 192 + fc * 4 + u) * 256 + t];
#pragma unroll
        for (int dd = 0; dd < 8; ++dd) {
          float4 f4 = *(const float4*)(sF + dd * 128 + fc * 4);
          acc[dd] += f4.x * w1v[0] + f4.y * w1v[1] + f4.z * w1v[2] + f4.w * w1v[3];
        }
      }
#pragma unroll
      for (int dd = 0; dd < 8; ++dd)
        ws_U[(h * 32 + dt * 8 + dd) * 256 + t] = acc[dd];
    } else {
      float acc = b1[h * 256 + t];
      for (int fc = 0; fc < 32; ++fc) {
        float w1v[4];
#pragma unroll
        for (int u = 0; u < 4; ++u) w1v[u] = W1[(h * 192 + fc * 4 + u) * 256 + t];
        float4 f4 = *(const float4*)(sF + fc * 4);
        acc += f4.x * w1v[0] + f4.y * w1v[1] + f4.z * w1v[2] + f4.w * w1v[3];
      }
      ws_c0[h * 256 + t] = acc;
    }

  } else {
    // ---------------- M range: 16 blocks/h, 16 k1-rows each
    const int r = bx - 224;
    const int h = r >> 4, kt = r & 15;
    float* s = sh;
#pragma unroll
    for (int i = 0; i < 12; ++i)
      s[i * 256 + t] = W2[h * 49152 + kt * 3072 + i * 256 + t];
    __syncthreads();
    float acc[16];
#pragma unroll
    for (int rr = 0; rr < 16; ++rr) acc[rr] = 0.f;
    float c1acc = 0.f;
    for (int vc = 0; vc < 48; ++vc) {
      float w1o[4], b2v[4];
#pragma unroll
      for (int u = 0; u < 4; ++u) {
        w1o[u] = W1o[(h * 192 + vc * 4 + u) * 256 + t];
        b2v[u] = b2[h * 192 + vc * 4 + u];
      }
      c1acc += b2v[0] * w1o[0] + b2v[1] * w1o[1] + b2v[2] * w1o[2] + b2v[3] * w1o[3];
#pragma unroll
      for (int rr = 0; rr < 16; ++rr) {
        float4 w2 = *(const float4*)(s + rr * 192 + vc * 4);
        acc[rr] += w2.x * w1o[0] + w2.y * w1o[1] + w2.z * w1o[2] + w2.w * w1o[3];
      }
    }
    if (kt == 0) ws_c1[h * 256 + t] = c1acc + b1o[h * 256 + t];
    __syncthreads();
#pragma unroll
    for (int rr = 0; rr < 16; ++rr) s[rr * 260 + t] = acc[rr];
    __syncthreads();
    const int k1l = t & 15, k2g = t >> 4;
#pragma unroll
    for (int it = 0; it < 16; ++it) {
      const int k2 = it * 16 + k2g;
      ws_Mbf[(h * 256 + k2) * 256 + kt * 16 + k1l] =
          (unsigned short)f2bf(s[k1l * 260 + k2]);
    }
  }
}

// ---------------------------------------------------------------- kB: G (LDS) -> P -> MFMA P@M -> effect
__global__ __launch_bounds__(256) void kB_main(
    const float* __restrict__ feat, const float* __restrict__ ws_w,
    const float* __restrict__ ws_U, const float* __restrict__ W1,
    const float* __restrict__ ws_ae, const float* __restrict__ ws_c0,
    const unsigned short* __restrict__ ws_Mbf, const float* __restrict__ ws_c1,
    const float* __restrict__ W2o, const float* __restrict__ b2o,
    float* __restrict__ out_eff) {
  const int bx = blockIdx.x;
  const int h = (bx & 7) * 4 + ((bx >> 3) & 3);   // XCD swizzle (bijective in bx&31)
  const int bt = bx >> 5;                   // 16 b per block
  const int b0 = bt * 16;
  const int t = threadIdx.x;

  __shared__ __align__(16) char smem[29696];
  short* sP   = (short*)smem;               // [16][264] bf16
  float* sG   = (float*)(smem + 8448);      // [16][260]
  float* sAe  = (float*)(smem + 25088);     // [16][64]
  float* sRed = (float*)(smem + 29184);     // [16][4]

  // ---- G in LDS: G[bi][k=t] = c0[k] + ae[bi]·W1[h,128:192,k]
  {
#pragma unroll
    for (int i = 0; i < 4; ++i) sAe[i * 256 + t] = ws_ae[b0 * 64 + i * 256 + t];
    float w1r[64];
#pragma unroll
    for (int j = 0; j < 64; ++j) w1r[j] = W1[(h * 192 + 128 + j) * 256 + t];
    const float c0v = ws_c0[h * 256 + t];
    __syncthreads();
#pragma unroll
    for (int bi = 0; bi < 16; ++bi) {
      float acc = c0v;
#pragma unroll
      for (int jc = 0; jc < 16; ++jc) {
        float4 a4 = *(const float4*)(sAe + bi * 64 + jc * 4);
        acc += a4.x * w1r[jc * 4 + 0] + a4.y * w1r[jc * 4 + 1]
             + a4.z * w1r[jc * 4 + 2] + a4.w * w1r[jc * 4 + 3];
      }
      sG[bi * 260 + t] = acc;
    }
  }
  __syncthreads();

  // ---- P: thread (bi = t>>4, k in {seg*64 + kg*4 + c}) -> bf16 LDS
  {
    const int bi = t >> 4, kg = t & 15;
    const int b = b0 + bi;
    float g[16], acc[16];
#pragma unroll
    for (int seg = 0; seg < 4; ++seg) {
      float4 g4 = *(const float4*)(sG + bi * 260 + seg * 64 + kg * 4);
      g[seg * 4 + 0] = g4.x; g[seg * 4 + 1] = g4.y;
      g[seg * 4 + 2] = g4.z; g[seg * 4 + 3] = g4.w;
      acc[seg * 4 + 0] = 0.f; acc[seg * 4 + 1] = 0.f;
      acc[seg * 4 + 2] = 0.f; acc[seg * 4 + 3] = 0.f;
    }
    const float* Up = ws_U + h * 8192 + kg * 4;
    for (int dc = 0; dc < 8; ++dc) {
      float4 z4 = *(const float4*)(feat + b * 32 + dc * 4);
      float4 w4 = *(const float4*)(ws_w + b * 32 + dc * 4);
      float zz[4] = {z4.x, z4.y, z4.z, z4.w};
      float wv[4] = {w4.x, w4.y, w4.z, w4.w};
#pragma unroll
      for (int dd = 0; dd < 4; ++dd) {
        const float* Ud = Up + (dc * 4 + dd) * 256;
#pragma unroll
        for (int seg = 0; seg < 4; ++seg) {
          float4 u4 = *(const float4*)(Ud + seg * 64);
          acc[seg * 4 + 0] += wv[dd] * fmaxf(zz[dd] * u4.x + g[seg * 4 + 0], 0.f);
          acc[seg * 4 + 1] += wv[dd] * fmaxf(zz[dd] * u4.y + g[seg * 4 + 1], 0.f);
          acc[seg * 4 + 2] += wv[dd] * fmaxf(zz[dd] * u4.z + g[seg * 4 + 2], 0.f);
          acc[seg * 4 + 3] += wv[dd] * fmaxf(zz[dd] * u4.w + g[seg * 4 + 3], 0.f);
        }
      }
    }
#pragma unroll
    for (int seg = 0; seg < 4; ++seg) {
      bf16x4 p;
#pragma unroll
      for (int j = 0; j < 4; ++j) p[j] = f2bf(acc[seg * 4 + j]);
      *(bf16x4*)(sP + bi * 264 + seg * 64 + kg * 4) = p;
    }
  }
  __syncthreads();

  // ---- MFMA: D[16 b][64 k2 per wave] = P @ M ; epilogue
  {
    const int wv = t >> 6;
    const int lane = t & 63;
    const int quad = lane >> 4, l15 = lane & 15;

    f32x4 acc[4];
    const f32x4 zero = {0.f, 0.f, 0.f, 0.f};
#pragma unroll
    for (int nt = 0; nt < 4; ++nt) acc[nt] = zero;

    float c1r[4], w2r[4];
#pragma unroll
    for (int nt = 0; nt < 4; ++nt) {
      const int col = wv * 64 + nt * 16 + l15;
      c1r[nt] = ws_c1[h * 256 + col];
      w2r[nt] = W2o[h * 256 + col];
    }
    const unsigned short* Mp = ws_Mbf + (size_t)(h * 256 + wv * 64) * 256;

#pragma unroll
    for (int kc = 0; kc < 8; ++kc) {
      bf16x8 a0 = *(const bf16x8*)(sP + l15 * 264 + kc * 32 + quad * 8);
      bf16x8 bfr[4];
#pragma unroll
      for (int nt = 0; nt < 4; ++nt)
        bfr[nt] = *(const bf16x8*)(Mp + (nt * 16 + l15) * 256 + kc * 32 + quad * 8);
#pragma unroll
      for (int nt = 0; nt < 4; ++nt)
        acc[nt] = __builtin_amdgcn_mfma_f32_16x16x32_bf16(a0, bfr[nt], acc[nt], 0, 0, 0);
    }
#pragma unroll
    for (int r = 0; r < 4; ++r) {
      float s = fmaxf(acc[0][r] + c1r[0], 0.f) * w2r[0]
              + fmaxf(acc[1][r] + c1r[1], 0.f) * w2r[1]
              + fmaxf(acc[2][r] + c1r[2], 0.f) * w2r[2]
              + fmaxf(acc[3][r] + c1r[3], 0.f) * w2r[3];
      s += __shfl_xor(s, 1, 64);
      s += __shfl_xor(s, 2, 64);
      s += __shfl_xor(s, 4, 64);
      s += __shfl_xor(s, 8, 64);
      if (l15 == 0) sRed[(quad * 4 + r) * 4 + wv] = s;
    }
  }
  __syncthreads();
  if (t < 16) {
    float v = sRed[t * 4] + sRed[t * 4 + 1] + sRed[t * 4 + 2] + sRed[t * 4 + 3] + b2o[h];
    out_eff[(b0 + t) * 32 + h] = v;
  }
}

// ----------------------------------------------------------------
extern "C" void kernel_launch(void* const* d_in, const int* in_sizes, int n_in,
                              void* d_out, int out_size, void* d_ws, size_t ws_size,
                              hipStream_t stream) {
  const float* feat = (const float*)d_in[0];
  const float* act  = (const float*)d_in[1];
  const float* Wq   = (const float*)d_in[2];
  const float* bq   = (const float*)d_in[3];
  const float* Wk   = (const float*)d_in[4];
  // d_in[5] = bk: cancels in softmax
  const float* Wav  = (const float*)d_in[6];
  const float* bav  = (const float*)d_in[7];
  const float* Wfv  = (const float*)d_in[8];
  const float* bfv  = (const float*)d_in[9];
  const float* W1   = (const float*)d_in[10];
  const float* b1   = (const float*)d_in[11];
  const float* W2   = (const float*)d_in[12];
  const float* b2   = (const float*)d_in[13];
  const float* W1o  = (const float*)d_in[14];
  const float* b1o  = (const float*)d_in[15];
  const float* W2o  = (const float*)d_in[16];
  const float* b2o  = (const float*)d_in[17];
  float* out = (float*)d_out;               // [0,16384): effect; rest: attn_weights
  float* ws = (float*)d_ws;

  float* ws_w  = ws;                                        // 16384
  float* ws_ae = ws + 16384;                                // 32768
  float* ws_U  = ws + 49152;                                // 262144
  float* ws_c0 = ws + 311296;                               // 8192
  float* ws_c1 = ws + 319488;                               // 8192
  unsigned short* ws_Mbf = (unsigned short*)(ws + 327680);  // 2097152 shorts

  hipLaunchKernelGGL(kA_prep, dim3(736), dim3(256), 0, stream,
                     feat, act, Wq, bq, Wk, Wav, bav, Wfv, bfv, W1, b1,
                     W2, b2, W1o, b1o, ws_w, ws_ae, ws_U, ws_c0, ws_Mbf, ws_c1,
                     out + 16384);
  hipLaunchKernelGGL(kB_main, dim3(1024), dim3(256), 0, stream,
                     feat, ws_w, ws_U, W1, ws_ae, ws_c0, ws_Mbf, ws_c1,
                     W2o, b2o, out);
}